// Round 6
// baseline (309.644 us; speedup 1.0000x reference)
//
#include <hip/hip_runtime.h>
#include <stdint.h>

typedef __bf16 bf16x8 __attribute__((ext_vector_type(8)));
typedef float f32x4 __attribute__((ext_vector_type(4)));
typedef unsigned short ushort8 __attribute__((ext_vector_type(8)));
typedef unsigned short ushort4v __attribute__((ext_vector_type(4)));

constexpr int CB = 4;
constexpr int CL = 2048;
constexpr int CD = 1024;
constexpr int CH = 16;
constexpr int CDH = 64;
constexpr int CM = CB * CL;  // 8192

__device__ __forceinline__ unsigned short f2bf(float f) {
  union { float f; unsigned u; } x; x.f = f;
  unsigned r = x.u + 0x7fffu + ((x.u >> 16) & 1u);
  return (unsigned short)(r >> 16);
}
__device__ __forceinline__ float bf2f(unsigned short b) {
  union { unsigned u; float f; } x; x.u = ((unsigned)b) << 16;
  return x.f;
}

__device__ __forceinline__ void gld_lds16(const void* g, void* l) {
  __builtin_amdgcn_global_load_lds((const __attribute__((address_space(1))) void*)g,
                                   (__attribute__((address_space(3))) void*)l, 16, 0, 0);
}

#define MFMA16(a, b, c) __builtin_amdgcn_mfma_f32_16x16x32_bf16((a), (b), (c), 0, 0, 0)

// ---------------- fp32 -> bf16 converts ----------------

__global__ __launch_bounds__(256) void cvt_kernel(const float* __restrict__ src,
                                                  unsigned short* __restrict__ dst) {
  const int i = blockIdx.x * 256 + threadIdx.x;
  const float4* s = (const float4*)src;
  float4 a = s[2 * i], b = s[2 * i + 1];
  ushort8 o;
  o[0] = f2bf(a.x); o[1] = f2bf(a.y); o[2] = f2bf(a.z); o[3] = f2bf(a.w);
  o[4] = f2bf(b.x); o[5] = f2bf(b.y); o[6] = f2bf(b.z); o[7] = f2bf(b.w);
  ((ushort8*)dst)[i] = o;
}

__global__ __launch_bounds__(256) void cvtw_kernel(const float* w0, const float* w1,
                                                   const float* w2, const float* w3,
                                                   unsigned short* o0, unsigned short* o1,
                                                   unsigned short* o2, unsigned short* o3) {
  const int which = blockIdx.x >> 9;
  const int i = (blockIdx.x & 511) * 256 + threadIdx.x;
  const float* s = which == 0 ? w0 : which == 1 ? w1 : which == 2 ? w2 : w3;
  unsigned short* d = which == 0 ? o0 : which == 1 ? o1 : which == 2 ? o2 : o3;
  const float4* sp = (const float4*)s;
  float4 a = sp[2 * i], b = sp[2 * i + 1];
  ushort8 o;
  o[0] = f2bf(a.x); o[1] = f2bf(a.y); o[2] = f2bf(a.z); o[3] = f2bf(a.w);
  o[4] = f2bf(b.x); o[5] = f2bf(b.y); o[6] = f2bf(b.z); o[7] = f2bf(b.w);
  ((ushort8*)d)[i] = o;
}

// ---------------- lengths from prefix mask ----------------

__global__ __launch_bounds__(256) void lens_kernel(const int* __restrict__ mask,
                                                   int* __restrict__ lens) {
  __shared__ int part[4];
  const int b = blockIdx.x;
  int cnt = 0;
  for (int i = threadIdx.x; i < CL; i += 256) cnt += (mask[b * CL + i] != 0) ? 1 : 0;
#pragma unroll
  for (int off = 32; off; off >>= 1) cnt += __shfl_down(cnt, off);
  if ((threadIdx.x & 63) == 0) part[threadIdx.x >> 6] = cnt;
  __syncthreads();
  if (threadIdx.x == 0) lens[b] = part[0] + part[1] + part[2] + part[3];
}

// ---------------- GEMM: C = (A * Bw^T + bias) * alpha ----------------
// 128x128 tile, BK=32, 8 waves (wave tile 32x64), double-buffered gld_lds staging.
// OMODE 0: bf16 row-major out. 1: f32 row-major out. 2: bf16 per-head transposed [B,H,DH,L].

template <int OMODE>
__global__ __launch_bounds__(512) void gemm_bt(const unsigned short* __restrict__ A,
                                               const unsigned short* __restrict__ Bw,
                                               const float* __restrict__ bias,
                                               void* __restrict__ Cout,
                                               int M, int N, int K, float alpha) {
  __shared__ unsigned short Asm[2][128 * 32];
  __shared__ unsigned short Bsm[2][128 * 32];
  const int tid = threadIdx.x;                       // 0..511
  const int w = tid >> 6, ln = tid & 63, lr = ln & 15, lq = ln >> 4;
  const int nbx = N >> 7;
  // bijective XCD swizzle (grid % 8 == 0)
  const int cpx = (int)gridDim.x >> 3;
  const int bid = ((int)blockIdx.x & 7) * cpx + ((int)blockIdx.x >> 3);
  const int bm = (bid / nbx) << 7;
  const int bn = (bid % nbx) << 7;
  const int wr = (w >> 1) << 5, wc = (w & 1) << 6;   // wave tile 32 rows x 64 cols

  f32x4 acc[2][4] = {};
  const int nkt = K >> 5;
  const int arow = tid >> 2, akc = (tid & 3) << 3;

  auto stage = [&](int buf, int k0) {
    gld_lds16(A + (size_t)(bm + arow) * K + k0 + akc, (void*)(Asm[buf] + w * 512));
    gld_lds16(Bw + (size_t)(bn + arow) * K + k0 + akc, (void*)(Bsm[buf] + w * 512));
  };

  stage(0, 0);
  __syncthreads();

  for (int kt = 0; kt < nkt; ++kt) {
    const int cur = kt & 1;
    if (kt + 1 < nkt) stage(cur ^ 1, (kt + 1) << 5);
    bf16x8 af[2], bfr[4];
#pragma unroll
    for (int f = 0; f < 2; ++f)
      af[f] = *(const bf16x8*)(Asm[cur] + ((wr + f * 16 + lr) * 32 + lq * 8));
#pragma unroll
    for (int f = 0; f < 4; ++f)
      bfr[f] = *(const bf16x8*)(Bsm[cur] + ((wc + f * 16 + lr) * 32 + lq * 8));
#pragma unroll
    for (int fm = 0; fm < 2; ++fm)
#pragma unroll
      for (int fn = 0; fn < 4; ++fn)
        acc[fm][fn] = MFMA16(af[fm], bfr[fn], acc[fm][fn]);
    __syncthreads();
  }

#pragma unroll
  for (int fm = 0; fm < 2; ++fm) {
    const int row0 = bm + wr + fm * 16 + lq * 4;
#pragma unroll
    for (int fn = 0; fn < 4; ++fn) {
      const int col = bn + wc + fn * 16 + lr;
      const float bb = bias[col];
      if (OMODE == 2) {
        const int b = row0 >> 11, lrow = row0 & (CL - 1);
        const int hh = col >> 6, dh = col & 63;
        ushort4v pk;
#pragma unroll
        for (int j = 0; j < 4; ++j) pk[j] = f2bf((acc[fm][fn][j] + bb) * alpha);
        *(ushort4v*)((unsigned short*)Cout +
                     (((size_t)((b * CH + hh) * CDH + dh)) << 11) + lrow) = pk;
      } else if (OMODE == 0) {
#pragma unroll
        for (int j = 0; j < 4; ++j)
          ((unsigned short*)Cout)[(size_t)(row0 + j) * N + col] =
              f2bf((acc[fm][fn][j] + bb) * alpha);
      } else {
#pragma unroll
        for (int j = 0; j < 4; ++j)
          ((float*)Cout)[(size_t)(row0 + j) * N + col] = (acc[fm][fn][j] + bb) * alpha;
      }
    }
  }
}

// ---------------- mean over L of each Vt row ----------------

__global__ __launch_bounds__(256) void meanv_kernel(const unsigned short* __restrict__ Vt,
                                                    float* __restrict__ meanv) {
  const int row = blockIdx.x * 4 + (threadIdx.x >> 6);
  const int ln = threadIdx.x & 63;
  const ushort8* p = (const ushort8*)(Vt + (size_t)row * CL);
  float s = 0.f;
#pragma unroll
  for (int it = 0; it < 4; ++it) {
    ushort8 v = p[it * 64 + ln];
#pragma unroll
    for (int j = 0; j < 8; ++j) s += bf2f(v[j]);
  }
#pragma unroll
  for (int off = 32; off; off >>= 1) s += __shfl_down(s, off);
  if (ln == 0) meanv[row] = s * (1.f / (float)CL);
}

// ---------------- flash attention, no-max softmax, single-wave blocks ----------
// One 64-thread block = one wave's 32 q-rows. No barriers, no split-K.
// Occupancy-first: __launch_bounds__(64,6) caps VGPR so 24 waves/CU can reside;
// 4096 fine-grained blocks pack tightly. Block map: xcd gets 8 (b,h) streams
// (4MB K+V = L2-fit); qt descending (heaviest first) across dispatch order.

__global__ __launch_bounds__(64, 6) void attn_kernel(const unsigned short* __restrict__ Qp,
                                                     const unsigned short* __restrict__ Kp,
                                                     const unsigned short* __restrict__ Vt,
                                                     const int* __restrict__ lens,
                                                     unsigned short* __restrict__ attno) {
  __shared__ unsigned short Ps[32][72];
  const int i = blockIdx.x;
  const int xcd = i & 7, bh8 = (i >> 3) & 7, slot = i >> 6;  // slot 0..63
  const int qt = 15 - (slot >> 2), wv = slot & 3;            // qt desc = heavy first
  const int bh = bh8 * 8 + xcd;
  const int b = bh >> 4, h = bh & 15;
  const int rowbase = (qt << 7) + (wv << 5);  // this wave's 32 q-rows
  const int len = lens[b];
  if (rowbase >= len) return;  // rows handled by padfix

  const int tid = threadIdx.x, lr = tid & 15, lq = tid >> 4;

  const unsigned short* Kbase = Kp + (size_t)(b * CL) * CD + h * 64;
  const unsigned short* Vbase = Vt + ((size_t)(bh * 64) << 11);
  const unsigned short* Qbase = Qp + (size_t)(b * CL + rowbase) * CD + h * 64;

  bf16x8 qa[2][2];
#pragma unroll
  for (int rs = 0; rs < 2; ++rs)
#pragma unroll
    for (int hf = 0; hf < 2; ++hf)
      qa[rs][hf] = *(const bf16x8*)(Qbase + (size_t)(rs * 16 + lr) * CD + hf * 32 + lq * 8);

  f32x4 o[2][4] = {};
  float lsum[2][4] = {};

  const int kdiag = rowbase >> 6;  // tile containing this wave's diagonal

  auto tile = [&](const int kt, const bool dm) {
    const int kb = kt << 6;

    bf16x8 kf[4][2];
#pragma unroll
    for (int cf = 0; cf < 4; ++cf)
#pragma unroll
      for (int hf = 0; hf < 2; ++hf)
        kf[cf][hf] =
            *(const bf16x8*)(Kbase + (size_t)(kb + cf * 16 + lr) * CD + hf * 32 + lq * 8);

#pragma unroll
    for (int rs = 0; rs < 2; ++rs) {
      f32x4 s[4];
#pragma unroll
      for (int cf = 0; cf < 4; ++cf) {
        f32x4 z = {};
        z = MFMA16(qa[rs][0], kf[cf][0], z);
        z = MFMA16(qa[rs][1], kf[cf][1], z);
        s[cf] = z;
      }
#pragma unroll
      for (int cf = 0; cf < 4; ++cf) {
#pragma unroll
        for (int j = 0; j < 4; ++j) {
          float p = __builtin_amdgcn_exp2f(s[cf][j]);
          if (dm) {
            const int key = kb + cf * 16 + lr;
            const int row = rowbase + rs * 16 + lq * 4 + j;
            p = (key > row) ? 0.f : p;
          }
          lsum[rs][j] += p;
          // truncating bf16 store of the f32 high half
          Ps[rs * 16 + lq * 4 + j][cf * 16 + lr] =
              (unsigned short)(__builtin_bit_cast(unsigned int, p) >> 16);
        }
      }
    }

    bf16x8 pa[2][2];
#pragma unroll
    for (int rs = 0; rs < 2; ++rs)
#pragma unroll
      for (int hf = 0; hf < 2; ++hf)
        pa[rs][hf] = *(const bf16x8*)(&Ps[rs * 16 + lr][hf * 32 + lq * 8]);

#pragma unroll
    for (int df = 0; df < 4; ++df) {
      const bf16x8 vb0 =
          *(const bf16x8*)(Vbase + (((size_t)(df * 16 + lr)) << 11) + kb + lq * 8);
      const bf16x8 vb1 =
          *(const bf16x8*)(Vbase + (((size_t)(df * 16 + lr)) << 11) + kb + 32 + lq * 8);
      o[0][df] = MFMA16(pa[0][0], vb0, o[0][df]);
      o[0][df] = MFMA16(pa[0][1], vb1, o[0][df]);
      o[1][df] = MFMA16(pa[1][0], vb0, o[1][df]);
      o[1][df] = MFMA16(pa[1][1], vb1, o[1][df]);
    }
  };

  for (int kt = 0; kt < kdiag; ++kt) tile(kt, false);
  tile(kdiag, true);

  float inv[2][4];
#pragma unroll
  for (int rs = 0; rs < 2; ++rs)
#pragma unroll
    for (int j = 0; j < 4; ++j) {
      float t = lsum[rs][j];
      t += __shfl_xor(t, 1);
      t += __shfl_xor(t, 2);
      t += __shfl_xor(t, 4);
      t += __shfl_xor(t, 8);
      inv[rs][j] = __builtin_amdgcn_rcpf(t);
    }

#pragma unroll
  for (int rs = 0; rs < 2; ++rs)
#pragma unroll
    for (int df = 0; df < 4; ++df)
#pragma unroll
      for (int j = 0; j < 4; ++j)
        attno[(size_t)(b * CL + rowbase + rs * 16 + lq * 4 + j) * CD + h * 64 + df * 16 +
              lr] = f2bf(o[rs][df][j] * inv[rs][j]);
}

// ---------------- padded-query fixup: uniform attention = mean of V rows -------

__global__ __launch_bounds__(256) void padfix_kernel(const int* __restrict__ lens,
                                                     const float* __restrict__ meanv,
                                                     unsigned short* __restrict__ attno) {
  const int q = blockIdx.x & (CL - 1);
  const int b = blockIdx.x >> 11;
  if (q < lens[b]) return;
#pragma unroll
  for (int i = 0; i < 4; ++i) {
    const int col = threadIdx.x + i * 256;
    attno[(size_t)(b * CL + q) * CD + col] = f2bf(meanv[b * CD + col]);
  }
}

// ---------------- launch ----------------

extern "C" void kernel_launch(void* const* d_in, const int* in_sizes, int n_in,
                              void* d_out, int out_size, void* d_ws, size_t ws_size,
                              hipStream_t stream) {
  const float* q  = (const float*)d_in[0];
  const float* k  = (const float*)d_in[1];
  const float* v  = (const float*)d_in[2];
  const int*   am = (const int*)d_in[3];
  const float* Wq = (const float*)d_in[4];
  const float* bq = (const float*)d_in[5];
  const float* Wk = (const float*)d_in[6];
  const float* bk = (const float*)d_in[7];
  const float* Wv = (const float*)d_in[8];
  const float* bv = (const float*)d_in[9];
  const float* Wc = (const float*)d_in[10];
  const float* bc = (const float*)d_in[11];
  float* out = (float*)d_out;

  unsigned short* Wqb = (unsigned short*)d_ws;
  unsigned short* Wkb = Wqb + (1 << 20);
  unsigned short* Wvb = Wkb + (1 << 20);
  unsigned short* Wcb = Wvb + (1 << 20);
  unsigned short* X   = Wcb + (1 << 20);          // staging / attn-out, CM*CD bf16
  unsigned short* Qp  = X  + (size_t)CM * CD;
  unsigned short* Kp  = Qp + (size_t)CM * CD;
  unsigned short* Vt  = Kp + (size_t)CM * CD;     // [B,H,DH,L]
  float* meanv = (float*)(Vt + (size_t)CM * CD);  // [B, D]
  int* lens = (int*)(meanv + CB * CD);

  cvtw_kernel<<<2048, 256, 0, stream>>>(Wq, Wk, Wv, Wc, Wqb, Wkb, Wvb, Wcb);
  lens_kernel<<<CB, 256, 0, stream>>>(am, lens);

  const int gg = (CM / 128) * (CD / 128);  // 512 blocks
  const float QSCALE = 0.125f * 1.44269504f;  // folded 1/sqrt(DH) * log2(e)

  cvt_kernel<<<4096, 256, 0, stream>>>(q, X);
  gemm_bt<0><<<gg, 512, 0, stream>>>(X, Wqb, bq, Qp, CM, CD, CD, QSCALE);
  cvt_kernel<<<4096, 256, 0, stream>>>(k, X);
  gemm_bt<0><<<gg, 512, 0, stream>>>(X, Wkb, bk, Kp, CM, CD, CD, 1.0f);
  cvt_kernel<<<4096, 256, 0, stream>>>(v, X);
  gemm_bt<2><<<gg, 512, 0, stream>>>(X, Wvb, bv, Vt, CM, CD, CD, 1.0f);

  meanv_kernel<<<1024, 256, 0, stream>>>(Vt, meanv);

  attn_kernel<<<4096, 64, 0, stream>>>(Qp, Kp, Vt, lens, X);
  padfix_kernel<<<CB * CL, 256, 0, stream>>>(lens, meanv, X);

  gemm_bt<1><<<gg, 512, 0, stream>>>(X, Wcb, bc, out, CM, CD, CD, 1.0f);
}

// Round 7
// 242.498 us; speedup vs baseline: 1.2769x; 1.2769x over previous
//
#include <hip/hip_runtime.h>
#include <stdint.h>

typedef __bf16 bf16x8 __attribute__((ext_vector_type(8)));
typedef float f32x4 __attribute__((ext_vector_type(4)));
typedef unsigned short ushort8 __attribute__((ext_vector_type(8)));
typedef unsigned short ushort4v __attribute__((ext_vector_type(4)));

constexpr int CB = 4;
constexpr int CL = 2048;
constexpr int CD = 1024;
constexpr int CH = 16;
constexpr int CDH = 64;
constexpr int CM = CB * CL;  // 8192

__device__ __forceinline__ unsigned short f2bf(float f) {
  union { float f; unsigned u; } x; x.f = f;
  unsigned r = x.u + 0x7fffu + ((x.u >> 16) & 1u);
  return (unsigned short)(r >> 16);
}
__device__ __forceinline__ float bf2f(unsigned short b) {
  union { unsigned u; float f; } x; x.u = ((unsigned)b) << 16;
  return x.f;
}

__device__ __forceinline__ void gld_lds16(const void* g, void* l) {
  __builtin_amdgcn_global_load_lds((const __attribute__((address_space(1))) void*)g,
                                   (__attribute__((address_space(3))) void*)l, 16, 0, 0);
}

#define MFMA16(a, b, c) __builtin_amdgcn_mfma_f32_16x16x32_bf16((a), (b), (c), 0, 0, 0)

// ---------------- fp32 -> bf16 converts ----------------

__global__ __launch_bounds__(256) void cvt_kernel(const float* __restrict__ src,
                                                  unsigned short* __restrict__ dst) {
  const int i = blockIdx.x * 256 + threadIdx.x;
  const float4* s = (const float4*)src;
  float4 a = s[2 * i], b = s[2 * i + 1];
  ushort8 o;
  o[0] = f2bf(a.x); o[1] = f2bf(a.y); o[2] = f2bf(a.z); o[3] = f2bf(a.w);
  o[4] = f2bf(b.x); o[5] = f2bf(b.y); o[6] = f2bf(b.z); o[7] = f2bf(b.w);
  ((ushort8*)dst)[i] = o;
}

__global__ __launch_bounds__(256) void cvtw_kernel(const float* w0, const float* w1,
                                                   const float* w2, const float* w3,
                                                   unsigned short* o0, unsigned short* o1,
                                                   unsigned short* o2, unsigned short* o3) {
  const int which = blockIdx.x >> 9;
  const int i = (blockIdx.x & 511) * 256 + threadIdx.x;
  const float* s = which == 0 ? w0 : which == 1 ? w1 : which == 2 ? w2 : w3;
  unsigned short* d = which == 0 ? o0 : which == 1 ? o1 : which == 2 ? o2 : o3;
  const float4* sp = (const float4*)s;
  float4 a = sp[2 * i], b = sp[2 * i + 1];
  ushort8 o;
  o[0] = f2bf(a.x); o[1] = f2bf(a.y); o[2] = f2bf(a.z); o[3] = f2bf(a.w);
  o[4] = f2bf(b.x); o[5] = f2bf(b.y); o[6] = f2bf(b.z); o[7] = f2bf(b.w);
  ((ushort8*)d)[i] = o;
}

// ---------------- lengths from prefix mask ----------------

__global__ __launch_bounds__(256) void lens_kernel(const int* __restrict__ mask,
                                                   int* __restrict__ lens) {
  __shared__ int part[4];
  const int b = blockIdx.x;
  int cnt = 0;
  for (int i = threadIdx.x; i < CL; i += 256) cnt += (mask[b * CL + i] != 0) ? 1 : 0;
#pragma unroll
  for (int off = 32; off; off >>= 1) cnt += __shfl_down(cnt, off);
  if ((threadIdx.x & 63) == 0) part[threadIdx.x >> 6] = cnt;
  __syncthreads();
  if (threadIdx.x == 0) lens[b] = part[0] + part[1] + part[2] + part[3];
}

// ---------------- GEMM: C = (A * Bw^T + bias) * alpha ----------------
// 128x128 tile, BK=32, 8 waves (wave tile 32x64), double-buffered gld_lds staging.
// OMODE 0: bf16 row-major out. 1: f32 row-major out. 2: bf16 per-head transposed [B,H,DH,L].

template <int OMODE>
__global__ __launch_bounds__(512) void gemm_bt(const unsigned short* __restrict__ A,
                                               const unsigned short* __restrict__ Bw,
                                               const float* __restrict__ bias,
                                               void* __restrict__ Cout,
                                               int M, int N, int K, float alpha) {
  __shared__ unsigned short Asm[2][128 * 32];
  __shared__ unsigned short Bsm[2][128 * 32];
  const int tid = threadIdx.x;                       // 0..511
  const int w = tid >> 6, ln = tid & 63, lr = ln & 15, lq = ln >> 4;
  const int nbx = N >> 7;
  // bijective XCD swizzle (grid % 8 == 0)
  const int cpx = (int)gridDim.x >> 3;
  const int bid = ((int)blockIdx.x & 7) * cpx + ((int)blockIdx.x >> 3);
  const int bm = (bid / nbx) << 7;
  const int bn = (bid % nbx) << 7;
  const int wr = (w >> 1) << 5, wc = (w & 1) << 6;   // wave tile 32 rows x 64 cols

  f32x4 acc[2][4] = {};
  const int nkt = K >> 5;
  const int arow = tid >> 2, akc = (tid & 3) << 3;

  auto stage = [&](int buf, int k0) {
    gld_lds16(A + (size_t)(bm + arow) * K + k0 + akc, (void*)(Asm[buf] + w * 512));
    gld_lds16(Bw + (size_t)(bn + arow) * K + k0 + akc, (void*)(Bsm[buf] + w * 512));
  };

  stage(0, 0);
  __syncthreads();

  for (int kt = 0; kt < nkt; ++kt) {
    const int cur = kt & 1;
    if (kt + 1 < nkt) stage(cur ^ 1, (kt + 1) << 5);
    bf16x8 af[2], bfr[4];
#pragma unroll
    for (int f = 0; f < 2; ++f)
      af[f] = *(const bf16x8*)(Asm[cur] + ((wr + f * 16 + lr) * 32 + lq * 8));
#pragma unroll
    for (int f = 0; f < 4; ++f)
      bfr[f] = *(const bf16x8*)(Bsm[cur] + ((wc + f * 16 + lr) * 32 + lq * 8));
#pragma unroll
    for (int fm = 0; fm < 2; ++fm)
#pragma unroll
      for (int fn = 0; fn < 4; ++fn)
        acc[fm][fn] = MFMA16(af[fm], bfr[fn], acc[fm][fn]);
    __syncthreads();
  }

#pragma unroll
  for (int fm = 0; fm < 2; ++fm) {
    const int row0 = bm + wr + fm * 16 + lq * 4;
#pragma unroll
    for (int fn = 0; fn < 4; ++fn) {
      const int col = bn + wc + fn * 16 + lr;
      const float bb = bias[col];
      if (OMODE == 2) {
        const int b = row0 >> 11, lrow = row0 & (CL - 1);
        const int hh = col >> 6, dh = col & 63;
        ushort4v pk;
#pragma unroll
        for (int j = 0; j < 4; ++j) pk[j] = f2bf((acc[fm][fn][j] + bb) * alpha);
        *(ushort4v*)((unsigned short*)Cout +
                     (((size_t)((b * CH + hh) * CDH + dh)) << 11) + lrow) = pk;
      } else if (OMODE == 0) {
#pragma unroll
        for (int j = 0; j < 4; ++j)
          ((unsigned short*)Cout)[(size_t)(row0 + j) * N + col] =
              f2bf((acc[fm][fn][j] + bb) * alpha);
      } else {
#pragma unroll
        for (int j = 0; j < 4; ++j)
          ((float*)Cout)[(size_t)(row0 + j) * N + col] = (acc[fm][fn][j] + bb) * alpha;
      }
    }
  }
}

// ---------------- mean over L of each Vt row ----------------

__global__ __launch_bounds__(256) void meanv_kernel(const unsigned short* __restrict__ Vt,
                                                    float* __restrict__ meanv) {
  const int row = blockIdx.x * 4 + (threadIdx.x >> 6);
  const int ln = threadIdx.x & 63;
  const ushort8* p = (const ushort8*)(Vt + (size_t)row * CL);
  float s = 0.f;
#pragma unroll
  for (int it = 0; it < 4; ++it) {
    ushort8 v = p[it * 64 + ln];
#pragma unroll
    for (int j = 0; j < 8; ++j) s += bf2f(v[j]);
  }
#pragma unroll
  for (int off = 32; off; off >>= 1) s += __shfl_down(s, off);
  if (ln == 0) meanv[row] = s * (1.f / (float)CL);
}

// ---------------- flash attention, no-max softmax, single-wave blocks ----------
// One 64-thread block = one wave's 32 q-rows. No barriers, no split-K.
// __launch_bounds__(64,4): VGPR bucket 128 (>= actual need ~80-112, NO spill),
// guaranteeing 4 waves/SIMD = 16 waves/CU cap; 4096 fine-grained blocks pack
// tightly. Block map: each XCD gets 8 (b,h) streams (4MB K+V = L2-fit); qt
// descending (heaviest first) across dispatch order.

__global__ __launch_bounds__(64, 4) void attn_kernel(const unsigned short* __restrict__ Qp,
                                                     const unsigned short* __restrict__ Kp,
                                                     const unsigned short* __restrict__ Vt,
                                                     const int* __restrict__ lens,
                                                     unsigned short* __restrict__ attno) {
  __shared__ unsigned short Ps[32][72];
  const int i = blockIdx.x;
  const int xcd = i & 7, bh8 = (i >> 3) & 7, slot = i >> 6;  // slot 0..63
  const int qt = 15 - (slot >> 2), wv = slot & 3;            // qt desc = heavy first
  const int bh = bh8 * 8 + xcd;
  const int b = bh >> 4, h = bh & 15;
  const int rowbase = (qt << 7) + (wv << 5);  // this wave's 32 q-rows
  const int len = lens[b];
  if (rowbase >= len) return;  // rows handled by padfix

  const int tid = threadIdx.x, lr = tid & 15, lq = tid >> 4;

  const unsigned short* Kbase = Kp + (size_t)(b * CL) * CD + h * 64;
  const unsigned short* Vbase = Vt + ((size_t)(bh * 64) << 11);
  const unsigned short* Qbase = Qp + (size_t)(b * CL + rowbase) * CD + h * 64;

  bf16x8 qa[2][2];
#pragma unroll
  for (int rs = 0; rs < 2; ++rs)
#pragma unroll
    for (int hf = 0; hf < 2; ++hf)
      qa[rs][hf] = *(const bf16x8*)(Qbase + (size_t)(rs * 16 + lr) * CD + hf * 32 + lq * 8);

  f32x4 o[2][4] = {};
  float lsum[2][4] = {};

  const int kdiag = rowbase >> 6;  // tile containing this wave's diagonal

  auto tile = [&](const int kt, const bool dm) {
    const int kb = kt << 6;

    bf16x8 kf[4][2];
#pragma unroll
    for (int cf = 0; cf < 4; ++cf)
#pragma unroll
      for (int hf = 0; hf < 2; ++hf)
        kf[cf][hf] =
            *(const bf16x8*)(Kbase + (size_t)(kb + cf * 16 + lr) * CD + hf * 32 + lq * 8);

#pragma unroll
    for (int rs = 0; rs < 2; ++rs) {
      f32x4 s[4];
#pragma unroll
      for (int cf = 0; cf < 4; ++cf) {
        f32x4 z = {};
        z = MFMA16(qa[rs][0], kf[cf][0], z);
        z = MFMA16(qa[rs][1], kf[cf][1], z);
        s[cf] = z;
      }
#pragma unroll
      for (int cf = 0; cf < 4; ++cf) {
#pragma unroll
        for (int j = 0; j < 4; ++j) {
          float p = __builtin_amdgcn_exp2f(s[cf][j]);
          if (dm) {
            const int key = kb + cf * 16 + lr;
            const int row = rowbase + rs * 16 + lq * 4 + j;
            p = (key > row) ? 0.f : p;
          }
          lsum[rs][j] += p;
          // truncating bf16 store of the f32 high half
          Ps[rs * 16 + lq * 4 + j][cf * 16 + lr] =
              (unsigned short)(__builtin_bit_cast(unsigned int, p) >> 16);
        }
      }
    }

    bf16x8 pa[2][2];
#pragma unroll
    for (int rs = 0; rs < 2; ++rs)
#pragma unroll
      for (int hf = 0; hf < 2; ++hf)
        pa[rs][hf] = *(const bf16x8*)(&Ps[rs * 16 + lr][hf * 32 + lq * 8]);

#pragma unroll
    for (int df = 0; df < 4; ++df) {
      const bf16x8 vb0 =
          *(const bf16x8*)(Vbase + (((size_t)(df * 16 + lr)) << 11) + kb + lq * 8);
      const bf16x8 vb1 =
          *(const bf16x8*)(Vbase + (((size_t)(df * 16 + lr)) << 11) + kb + 32 + lq * 8);
      o[0][df] = MFMA16(pa[0][0], vb0, o[0][df]);
      o[0][df] = MFMA16(pa[0][1], vb1, o[0][df]);
      o[1][df] = MFMA16(pa[1][0], vb0, o[1][df]);
      o[1][df] = MFMA16(pa[1][1], vb1, o[1][df]);
    }
  };

  for (int kt = 0; kt < kdiag; ++kt) tile(kt, false);
  tile(kdiag, true);

  float inv[2][4];
#pragma unroll
  for (int rs = 0; rs < 2; ++rs)
#pragma unroll
    for (int j = 0; j < 4; ++j) {
      float t = lsum[rs][j];
      t += __shfl_xor(t, 1);
      t += __shfl_xor(t, 2);
      t += __shfl_xor(t, 4);
      t += __shfl_xor(t, 8);
      inv[rs][j] = __builtin_amdgcn_rcpf(t);
    }

#pragma unroll
  for (int rs = 0; rs < 2; ++rs)
#pragma unroll
    for (int df = 0; df < 4; ++df)
#pragma unroll
      for (int j = 0; j < 4; ++j)
        attno[(size_t)(b * CL + rowbase + rs * 16 + lq * 4 + j) * CD + h * 64 + df * 16 +
              lr] = f2bf(o[rs][df][j] * inv[rs][j]);
}

// ---------------- padded-query fixup: uniform attention = mean of V rows -------

__global__ __launch_bounds__(256) void padfix_kernel(const int* __restrict__ lens,
                                                     const float* __restrict__ meanv,
                                                     unsigned short* __restrict__ attno) {
  const int q = blockIdx.x & (CL - 1);
  const int b = blockIdx.x >> 11;
  if (q < lens[b]) return;
#pragma unroll
  for (int i = 0; i < 4; ++i) {
    const int col = threadIdx.x + i * 256;
    attno[(size_t)(b * CL + q) * CD + col] = f2bf(meanv[b * CD + col]);
  }
}

// ---------------- launch ----------------

extern "C" void kernel_launch(void* const* d_in, const int* in_sizes, int n_in,
                              void* d_out, int out_size, void* d_ws, size_t ws_size,
                              hipStream_t stream) {
  const float* q  = (const float*)d_in[0];
  const float* k  = (const float*)d_in[1];
  const float* v  = (const float*)d_in[2];
  const int*   am = (const int*)d_in[3];
  const float* Wq = (const float*)d_in[4];
  const float* bq = (const float*)d_in[5];
  const float* Wk = (const float*)d_in[6];
  const float* bk = (const float*)d_in[7];
  const float* Wv = (const float*)d_in[8];
  const float* bv = (const float*)d_in[9];
  const float* Wc = (const float*)d_in[10];
  const float* bc = (const float*)d_in[11];
  float* out = (float*)d_out;

  unsigned short* Wqb = (unsigned short*)d_ws;
  unsigned short* Wkb = Wqb + (1 << 20);
  unsigned short* Wvb = Wkb + (1 << 20);
  unsigned short* Wcb = Wvb + (1 << 20);
  unsigned short* X   = Wcb + (1 << 20);          // staging / attn-out, CM*CD bf16
  unsigned short* Qp  = X  + (size_t)CM * CD;
  unsigned short* Kp  = Qp + (size_t)CM * CD;
  unsigned short* Vt  = Kp + (size_t)CM * CD;     // [B,H,DH,L]
  float* meanv = (float*)(Vt + (size_t)CM * CD);  // [B, D]
  int* lens = (int*)(meanv + CB * CD);

  cvtw_kernel<<<2048, 256, 0, stream>>>(Wq, Wk, Wv, Wc, Wqb, Wkb, Wvb, Wcb);
  lens_kernel<<<CB, 256, 0, stream>>>(am, lens);

  const int gg = (CM / 128) * (CD / 128);  // 512 blocks
  const float QSCALE = 0.125f * 1.44269504f;  // folded 1/sqrt(DH) * log2(e)

  cvt_kernel<<<4096, 256, 0, stream>>>(q, X);
  gemm_bt<0><<<gg, 512, 0, stream>>>(X, Wqb, bq, Qp, CM, CD, CD, QSCALE);
  cvt_kernel<<<4096, 256, 0, stream>>>(k, X);
  gemm_bt<0><<<gg, 512, 0, stream>>>(X, Wkb, bk, Kp, CM, CD, CD, 1.0f);
  cvt_kernel<<<4096, 256, 0, stream>>>(v, X);
  gemm_bt<2><<<gg, 512, 0, stream>>>(X, Wvb, bv, Vt, CM, CD, CD, 1.0f);

  meanv_kernel<<<1024, 256, 0, stream>>>(Vt, meanv);

  attn_kernel<<<4096, 64, 0, stream>>>(Qp, Kp, Vt, lens, X);
  padfix_kernel<<<CB * CL, 256, 0, stream>>>(lens, meanv, X);

  gemm_bt<1><<<gg, 512, 0, stream>>>(X, Wcb, bc, out, CM, CD, CD, 1.0f);
}